// Round 2
// baseline (374.298 us; speedup 1.0000x reference)
//
#include <hip/hip_runtime.h>
#include <stdint.h>

#define M_DIM 8192
#define N_DIM 8192
#define K_DIM 1024

typedef int int4v __attribute__((ext_vector_type(4)));

// ---- async global->LDS, 16B per lane (m97's key step: 517->874 TF) ----
__device__ __forceinline__ void gload16(const char* g, char* l) {
    __builtin_amdgcn_global_load_lds(
        (__attribute__((address_space(1))) void*)(void*)const_cast<char*>(g),
        (__attribute__((address_space(3))) void*)l,
        16, 0, 0);
}

__device__ __forceinline__ int sat8(int v) {
    v = v > 127 ? 127 : v;
    v = v < -128 ? -128 : v;
    return v;
}

// ---- pack a: int32 [M][K] -> int8 [M][K], 4 elems/thread, fully coalesced ----
__global__ __launch_bounds__(256) void pack_a_kernel(const int* __restrict__ a,
                                                     int* __restrict__ out) {
    int i = blockIdx.x * 256 + threadIdx.x;     // one per 4 source elements
    int4 v = ((const int4*)a)[i];
    out[i] = (v.x & 0xff) | ((v.y & 0xff) << 8) |
             ((v.z & 0xff) << 16) | ((v.w & 0xff) << 24);
}

// ---- pack b: int32 [K][N] -> int8 [N][K] (transpose via LDS tile) ----
__global__ __launch_bounds__(256) void pack_b_kernel(const int* __restrict__ b,
                                                     char* __restrict__ out) {
    __shared__ char tile[64][68];               // +4 pad breaks transpose conflicts
    const int n0 = blockIdx.x * 64;
    const int k0 = blockIdx.y * 64;
    const int t  = threadIdx.x;
    const int tr  = t >> 4;                     // 0..15
    const int tc4 = (t & 15) << 2;              // 0,4,..,60
#pragma unroll
    for (int j = 0; j < 4; ++j) {
        int row = tr + j * 16;                  // k within tile
        int4 v = *(const int4*)&b[(size_t)(k0 + row) * N_DIM + n0 + tc4];
        tile[row][tc4 + 0] = (char)v.x;
        tile[row][tc4 + 1] = (char)v.y;
        tile[row][tc4 + 2] = (char)v.z;
        tile[row][tc4 + 3] = (char)v.w;
    }
    __syncthreads();
#pragma unroll
    for (int j = 0; j < 4; ++j) {
        int n = tr + j * 16;                    // n within tile
        int pk = (tile[tc4 + 0][n] & 0xff) |
                 ((tile[tc4 + 1][n] & 0xff) << 8) |
                 ((tile[tc4 + 2][n] & 0xff) << 16) |
                 ((tile[tc4 + 3][n] & 0xff) << 24);
        *(int*)&out[(size_t)(n0 + n) * K_DIM + k0 + tc4] = pk;
    }
}

// ---- GEMM: 128x128 tile, BK=64, 4 waves, 4x4 16x16x64 i8 MFMAs per wave ----
__global__ __launch_bounds__(256) void gemm_i8_kernel(const char* __restrict__ A8,
                                                      const char* __restrict__ B8,
                                                      int* __restrict__ C) {
    __shared__ __align__(16) char As[128 * 64];   // [m][k], 64B rows
    __shared__ __align__(16) char Bs[128 * 64];   // [n][k], 64B rows

    const int t    = threadIdx.x;
    const int bn   = blockIdx.x;
    const int bm   = blockIdx.y;
    const int lane = t & 63;
    const int wave = t >> 6;
    const int wm   = wave >> 1;                  // 2x2 wave grid, 64x64 per wave
    const int wn   = wave & 1;
    const int quad = lane >> 4;
    const int l16  = lane & 15;

    const size_t aBase = (size_t)(bm * 128) * K_DIM;
    const size_t bBase = (size_t)(bn * 128) * K_DIM;

    // staging: 2 x 16B per thread per operand; LDS dest is lane-contiguous
    const int f0 = t * 16;
    const int r0 = f0 >> 6, c0 = f0 & 63;
    const int f1 = 4096 + t * 16;
    const int r1 = f1 >> 6, c1 = f1 & 63;

    int4v acc[4][4] = {};

    for (int kt = 0; kt < K_DIM / 64; ++kt) {
        const int kOff = kt * 64;
        gload16(A8 + aBase + (size_t)r0 * K_DIM + kOff + c0, As + f0);
        gload16(A8 + aBase + (size_t)r1 * K_DIM + kOff + c1, As + f1);
        gload16(B8 + bBase + (size_t)r0 * K_DIM + kOff + c0, Bs + f0);
        gload16(B8 + bBase + (size_t)r1 * K_DIM + kOff + c1, Bs + f1);
        __syncthreads();   // drains vmcnt -> staged data visible

        int4v af[4], bf[4];
#pragma unroll
        for (int mi = 0; mi < 4; ++mi)
            af[mi] = *(const int4v*)&As[(wm * 64 + mi * 16 + l16) * 64 + quad * 16];
#pragma unroll
        for (int ni = 0; ni < 4; ++ni)
            bf[ni] = *(const int4v*)&Bs[(wn * 64 + ni * 16 + l16) * 64 + quad * 16];

#pragma unroll
        for (int mi = 0; mi < 4; ++mi)
#pragma unroll
            for (int ni = 0; ni < 4; ++ni)
                acc[mi][ni] = __builtin_amdgcn_mfma_i32_16x16x64_i8(
                    af[mi], bf[ni], acc[mi][ni], 0, 0, 0);

        __syncthreads();   // LDS reads done before next stage overwrites
    }

    // epilogue: C/D layout col=lane&15, row=4*quad+reg; SATURATE to int8, store int32
    // (np reference saturates the fp32->int8 cast: round-0 absmax=127 proves no wrap)
    const int mBase = bm * 128 + wm * 64;
    const int nBase = bn * 128 + wn * 64;
#pragma unroll
    for (int mi = 0; mi < 4; ++mi) {
#pragma unroll
        for (int ni = 0; ni < 4; ++ni) {
            const int col = nBase + ni * 16 + l16;
#pragma unroll
            for (int r = 0; r < 4; ++r) {
                const int row = mBase + mi * 16 + quad * 4 + r;
                C[(size_t)row * N_DIM + col] = sat8(acc[mi][ni][r]);
            }
        }
    }
}

// ---- fallback (only if ws_size < 16MB): direct int32 GEMM, slow but correct ----
__global__ __launch_bounds__(256) void gemm_naive_kernel(const int* __restrict__ a,
                                                         const int* __restrict__ b,
                                                         int* __restrict__ C) {
    const int col = blockIdx.x * 256 + threadIdx.x;
    const int row = blockIdx.y;
    int acc = 0;
    for (int k = 0; k < K_DIM; ++k)
        acc += a[(size_t)row * K_DIM + k] * b[(size_t)k * N_DIM + col];
    C[(size_t)row * N_DIM + col] = sat8(acc);
}

extern "C" void kernel_launch(void* const* d_in, const int* in_sizes, int n_in,
                              void* d_out, int out_size, void* d_ws, size_t ws_size,
                              hipStream_t stream) {
    const int* a = (const int*)d_in[0];
    const int* b = (const int*)d_in[1];
    // alpha_row (d_in[2]) / alpha_col (d_in[3]) are unused in this variant.
    int* out = (int*)d_out;

    const size_t needed = 2 * (size_t)M_DIM * K_DIM;   // 16 MB packed operands
    if (ws_size < needed) {
        gemm_naive_kernel<<<dim3(N_DIM / 256, M_DIM), 256, 0, stream>>>(a, b, out);
        return;
    }

    char* A8 = (char*)d_ws;                          // 8 MB
    char* B8 = A8 + (size_t)M_DIM * K_DIM;           // 8 MB

    pack_a_kernel<<<(M_DIM * K_DIM / 4) / 256, 256, 0, stream>>>(a, (int*)A8);
    pack_b_kernel<<<dim3(N_DIM / 64, K_DIM / 64), 256, 0, stream>>>(b, B8);
    gemm_i8_kernel<<<dim3(N_DIM / 128, M_DIM / 128), 256, 0, stream>>>(A8, B8, out);
}

// Round 3
// 373.436 us; speedup vs baseline: 1.0023x; 1.0023x over previous
//
#include <hip/hip_runtime.h>
#include <stdint.h>

#define M_DIM 8192
#define N_DIM 8192
#define K_DIM 1024

typedef int int4v __attribute__((ext_vector_type(4)));

// ---- async global->LDS, 16B per lane (m97's key step: 517->874 TF) ----
__device__ __forceinline__ void gload16(const char* g, char* l) {
    __builtin_amdgcn_global_load_lds(
        (__attribute__((address_space(1))) void*)(void*)const_cast<char*>(g),
        (__attribute__((address_space(3))) void*)l,
        16, 0, 0);
}

__device__ __forceinline__ int sat8(int v) {
    v = v > 127 ? 127 : v;
    v = v < -128 ? -128 : v;
    return v;
}

// ---- pack a: int32 [M][K] -> int8 [M][K], 4 elems/thread, fully coalesced ----
__global__ __launch_bounds__(256) void pack_a_kernel(const int* __restrict__ a,
                                                     int* __restrict__ out) {
    int i = blockIdx.x * 256 + threadIdx.x;     // one per 4 source elements
    int4 v = ((const int4*)a)[i];
    out[i] = (v.x & 0xff) | ((v.y & 0xff) << 8) |
             ((v.z & 0xff) << 16) | ((v.w & 0xff) << 24);
}

// ---- pack b: int32 [K][N] -> int8 [N][K] (transpose via LDS tile) ----
__global__ __launch_bounds__(256) void pack_b_kernel(const int* __restrict__ b,
                                                     char* __restrict__ out) {
    __shared__ char tile[64][68];               // +4 pad breaks transpose conflicts
    const int n0 = blockIdx.x * 64;
    const int k0 = blockIdx.y * 64;
    const int t  = threadIdx.x;
    const int tr  = t >> 4;                     // 0..15
    const int tc4 = (t & 15) << 2;              // 0,4,..,60
#pragma unroll
    for (int j = 0; j < 4; ++j) {
        int row = tr + j * 16;                  // k within tile
        int4 v = *(const int4*)&b[(size_t)(k0 + row) * N_DIM + n0 + tc4];
        tile[row][tc4 + 0] = (char)v.x;
        tile[row][tc4 + 1] = (char)v.y;
        tile[row][tc4 + 2] = (char)v.z;
        tile[row][tc4 + 3] = (char)v.w;
    }
    __syncthreads();
#pragma unroll
    for (int j = 0; j < 4; ++j) {
        int n = tr + j * 16;                    // n within tile
        int pk = (tile[tc4 + 0][n] & 0xff) |
                 ((tile[tc4 + 1][n] & 0xff) << 8) |
                 ((tile[tc4 + 2][n] & 0xff) << 16) |
                 ((tile[tc4 + 3][n] & 0xff) << 24);
        *(int*)&out[(size_t)(n0 + n) * K_DIM + k0 + tc4] = pk;
    }
}

// ---- GEMM: 128x128 tile, BK=64, 4 waves, 4x4 16x16x64 i8 MFMAs per wave ----
// LDS layout is XOR-swizzled to kill the 8-way read conflict of the plain
// [row][64B] layout: element (row r, 16B-block kb) lives at block kb^((r>>1)&3).
// Swizzle is applied on the GLOBAL source address during global_load_lds
// (LDS side must stay lane-contiguous), and inverted at fragment-read time.
__global__ __launch_bounds__(256) void gemm_i8_kernel(const char* __restrict__ A8,
                                                      const char* __restrict__ B8,
                                                      int* __restrict__ C) {
    __shared__ __align__(16) char As[128 * 64];   // [m][k-swizzled], 64B rows
    __shared__ __align__(16) char Bs[128 * 64];   // [n][k-swizzled], 64B rows

    const int t    = threadIdx.x;
    const int bn   = blockIdx.x;
    const int bm   = blockIdx.y;
    const int lane = t & 63;
    const int wave = t >> 6;
    const int wm   = wave >> 1;                  // 2x2 wave grid, 64x64 per wave
    const int wn   = wave & 1;
    const int quad = lane >> 4;
    const int l16  = lane & 15;

    const size_t aBase = (size_t)(bm * 128) * K_DIM;
    const size_t bBase = (size_t)(bn * 128) * K_DIM;

    // staging: slot f = t*16 -> LDS row r=f>>6, block cb=(f>>4)&3.
    // that slot must hold global k-block cb^((r>>1)&3).
    const int f0 = t * 16;
    const int r0 = t >> 2;
    const int g0 = (((t & 3) ^ ((r0 >> 1) & 3)) << 4);   // swizzled k-offset in row
    const int f1 = 4096 + t * 16;
    const int r1 = 64 + (t >> 2);
    const int g1 = (((t & 3) ^ ((r1 >> 1) & 3)) << 4);

    // reader swizzle: row = (mult of 16) + l16 -> ((row>>1)&3) == ((l16>>1)&3)
    const int swz = (l16 >> 1) & 3;
    const int aOff0 = ((quad ^ swz) << 4);                // k-block offset in row

    int4v acc[4][4] = {};

    for (int kt = 0; kt < K_DIM / 64; ++kt) {
        const int kOff = kt * 64;
        gload16(A8 + aBase + (size_t)r0 * K_DIM + kOff + g0, As + f0);
        gload16(A8 + aBase + (size_t)r1 * K_DIM + kOff + g1, As + f1);
        gload16(B8 + bBase + (size_t)r0 * K_DIM + kOff + g0, Bs + f0);
        gload16(B8 + bBase + (size_t)r1 * K_DIM + kOff + g1, Bs + f1);
        __syncthreads();   // drains vmcnt -> staged data visible

        int4v af[4], bf[4];
#pragma unroll
        for (int mi = 0; mi < 4; ++mi)
            af[mi] = *(const int4v*)&As[(wm * 64 + mi * 16 + l16) * 64 + aOff0];
#pragma unroll
        for (int ni = 0; ni < 4; ++ni)
            bf[ni] = *(const int4v*)&Bs[(wn * 64 + ni * 16 + l16) * 64 + aOff0];

#pragma unroll
        for (int mi = 0; mi < 4; ++mi)
#pragma unroll
            for (int ni = 0; ni < 4; ++ni)
                acc[mi][ni] = __builtin_amdgcn_mfma_i32_16x16x64_i8(
                    af[mi], bf[ni], acc[mi][ni], 0, 0, 0);

        __syncthreads();   // LDS reads done before next stage overwrites
    }

    // epilogue: C/D layout col=lane&15, row=4*quad+reg; SATURATE to int8, store int32
    const int mBase = bm * 128 + wm * 64;
    const int nBase = bn * 128 + wn * 64;
#pragma unroll
    for (int mi = 0; mi < 4; ++mi) {
#pragma unroll
        for (int ni = 0; ni < 4; ++ni) {
            const int col = nBase + ni * 16 + l16;
#pragma unroll
            for (int r = 0; r < 4; ++r) {
                const int row = mBase + mi * 16 + quad * 4 + r;
                C[(size_t)row * N_DIM + col] = sat8(acc[mi][ni][r]);
            }
        }
    }
}

// ---- fallback (only if ws_size < 16MB): direct int32 GEMM, slow but correct ----
__global__ __launch_bounds__(256) void gemm_naive_kernel(const int* __restrict__ a,
                                                         const int* __restrict__ b,
                                                         int* __restrict__ C) {
    const int col = blockIdx.x * 256 + threadIdx.x;
    const int row = blockIdx.y;
    int acc = 0;
    for (int k = 0; k < K_DIM; ++k)
        acc += a[(size_t)row * K_DIM + k] * b[(size_t)k * N_DIM + col];
    C[(size_t)row * N_DIM + col] = sat8(acc);
}

extern "C" void kernel_launch(void* const* d_in, const int* in_sizes, int n_in,
                              void* d_out, int out_size, void* d_ws, size_t ws_size,
                              hipStream_t stream) {
    const int* a = (const int*)d_in[0];
    const int* b = (const int*)d_in[1];
    // alpha_row (d_in[2]) / alpha_col (d_in[3]) are unused in this variant.
    int* out = (int*)d_out;

    const size_t needed = 2 * (size_t)M_DIM * K_DIM;   // 16 MB packed operands
    if (ws_size < needed) {
        gemm_naive_kernel<<<dim3(N_DIM / 256, M_DIM), 256, 0, stream>>>(a, b, out);
        return;
    }

    char* A8 = (char*)d_ws;                          // 8 MB
    char* B8 = A8 + (size_t)M_DIM * K_DIM;           // 8 MB

    pack_a_kernel<<<(M_DIM * K_DIM / 4) / 256, 256, 0, stream>>>(a, (int*)A8);
    pack_b_kernel<<<dim3(N_DIM / 64, K_DIM / 64), 256, 0, stream>>>(b, B8);
    gemm_i8_kernel<<<dim3(N_DIM / 128, M_DIM / 128), 256, 0, stream>>>(A8, B8, out);
}

// Round 4
// 366.147 us; speedup vs baseline: 1.0223x; 1.0199x over previous
//
#include <hip/hip_runtime.h>
#include <stdint.h>

#define M_DIM 8192
#define N_DIM 8192
#define K_DIM 1024
#define BK    128          // K per LDS stage: 32 KB total LDS (m97's proven footprint)

typedef int int4v __attribute__((ext_vector_type(4)));

// ---- async global->LDS, 16B per lane (m97's key step: 517->874 TF) ----
__device__ __forceinline__ void gload16(const char* g, char* l) {
    __builtin_amdgcn_global_load_lds(
        (__attribute__((address_space(1))) void*)(void*)const_cast<char*>(g),
        (__attribute__((address_space(3))) void*)l,
        16, 0, 0);
}

__device__ __forceinline__ int sat8(int v) {
    v = v > 127 ? 127 : v;
    v = v < -128 ? -128 : v;
    return v;
}

// ---- pack a: int32 [M][K] -> int8 [M][K], 4 elems/thread, fully coalesced ----
__global__ __launch_bounds__(256) void pack_a_kernel(const int* __restrict__ a,
                                                     int* __restrict__ out) {
    int i = blockIdx.x * 256 + threadIdx.x;     // one per 4 source elements
    int4 v = ((const int4*)a)[i];
    out[i] = (v.x & 0xff) | ((v.y & 0xff) << 8) |
             ((v.z & 0xff) << 16) | ((v.w & 0xff) << 24);
}

// ---- pack b: int32 [K][N] -> int8 [N][K] (transpose via LDS tile) ----
__global__ __launch_bounds__(256) void pack_b_kernel(const int* __restrict__ b,
                                                     char* __restrict__ out) {
    __shared__ char tile[64][68];               // +4 pad breaks transpose conflicts
    const int n0 = blockIdx.x * 64;
    const int k0 = blockIdx.y * 64;
    const int t  = threadIdx.x;
    const int tr  = t >> 4;                     // 0..15
    const int tc4 = (t & 15) << 2;              // 0,4,..,60
#pragma unroll
    for (int j = 0; j < 4; ++j) {
        int row = tr + j * 16;                  // k within tile
        int4 v = *(const int4*)&b[(size_t)(k0 + row) * N_DIM + n0 + tc4];
        tile[row][tc4 + 0] = (char)v.x;
        tile[row][tc4 + 1] = (char)v.y;
        tile[row][tc4 + 2] = (char)v.z;
        tile[row][tc4 + 3] = (char)v.w;
    }
    __syncthreads();
#pragma unroll
    for (int j = 0; j < 4; ++j) {
        int n = tr + j * 16;                    // n within tile
        int pk = (tile[tc4 + 0][n] & 0xff) |
                 ((tile[tc4 + 1][n] & 0xff) << 8) |
                 ((tile[tc4 + 2][n] & 0xff) << 16) |
                 ((tile[tc4 + 3][n] & 0xff) << 24);
        *(int*)&out[(size_t)(n0 + n) * K_DIM + k0 + tc4] = pk;
    }
}

// ---- GEMM: 128x128 tile, BK=128 (8 barriers total), 4 waves, i8 MFMA ----
// LDS per operand = 2 planes x [128 rows][64 B]: each 64-element K-half keeps
// the 64 B-row substructure, which is bank-BALANCED for ds_read_b128
// (each of 32 banks services exactly 8 of the 256 dword phases — verified by
// round-3's neutral swizzle experiment). BK=128 halves the number of
// vmcnt(0)+barrier drains vs BK=64 at the same 32 KB LDS footprint.
__global__ __launch_bounds__(256) void gemm_i8_kernel(const char* __restrict__ A8,
                                                      const char* __restrict__ B8,
                                                      int* __restrict__ C) {
    __shared__ __align__(16) char As[2 * 128 * 64];   // [plane][m][k64]
    __shared__ __align__(16) char Bs[2 * 128 * 64];   // [plane][n][k64]

    const int t    = threadIdx.x;
    const int bn   = blockIdx.x;
    const int bm   = blockIdx.y;
    const int lane = t & 63;
    const int wave = t >> 6;
    const int wm   = wave >> 1;                  // 2x2 wave grid, 64x64 per wave
    const int wn   = wave & 1;
    const int quad = lane >> 4;
    const int l16  = lane & 15;

    const size_t aBase = (size_t)(bm * 128) * K_DIM;
    const size_t bBase = (size_t)(bn * 128) * K_DIM;

    // staging: 4 slots/operand/thread, 16 B each. slot s covers LDS offset
    // f = s*4096 + t*16 -> plane p=s>>1, row r=(s&1)*64 + t>>2, col c=(t&3)*16.
    const int sr = t >> 2;                       // row within 64-row half
    const int sc = (t & 3) << 4;                 // 16B col within 64B row

    int4v acc[4][4] = {};

    for (int kt = 0; kt < K_DIM / BK; ++kt) {
        const int kOff = kt * BK;
#pragma unroll
        for (int s = 0; s < 4; ++s) {
            const int p = s >> 1;                // K64-half
            const int r = ((s & 1) << 6) + sr;   // tile row
            const int f = s * 4096 + t * 16;     // LDS flat offset
            gload16(A8 + aBase + (size_t)r * K_DIM + kOff + p * 64 + sc, As + f);
            gload16(B8 + bBase + (size_t)r * K_DIM + kOff + p * 64 + sc, Bs + f);
        }
        __syncthreads();   // drains vmcnt -> staged data visible

#pragma unroll
        for (int h = 0; h < 2; ++h) {            // two K64-halves per stage
            int4v af[4], bf[4];
#pragma unroll
            for (int mi = 0; mi < 4; ++mi)
                af[mi] = *(const int4v*)
                    &As[h * 8192 + (wm * 64 + mi * 16 + l16) * 64 + quad * 16];
#pragma unroll
            for (int ni = 0; ni < 4; ++ni)
                bf[ni] = *(const int4v*)
                    &Bs[h * 8192 + (wn * 64 + ni * 16 + l16) * 64 + quad * 16];

#pragma unroll
            for (int mi = 0; mi < 4; ++mi)
#pragma unroll
                for (int ni = 0; ni < 4; ++ni)
                    acc[mi][ni] = __builtin_amdgcn_mfma_i32_16x16x64_i8(
                        af[mi], bf[ni], acc[mi][ni], 0, 0, 0);
        }

        __syncthreads();   // LDS reads done before next stage overwrites
    }

    // epilogue: C/D layout col=lane&15, row=4*quad+reg; SATURATE to int8, store int32
    const int mBase = bm * 128 + wm * 64;
    const int nBase = bn * 128 + wn * 64;
#pragma unroll
    for (int mi = 0; mi < 4; ++mi) {
#pragma unroll
        for (int ni = 0; ni < 4; ++ni) {
            const int col = nBase + ni * 16 + l16;
#pragma unroll
            for (int r = 0; r < 4; ++r) {
                const int row = mBase + mi * 16 + quad * 4 + r;
                C[(size_t)row * N_DIM + col] = sat8(acc[mi][ni][r]);
            }
        }
    }
}

// ---- fallback (only if ws_size < 16MB): direct int32 GEMM, slow but correct ----
__global__ __launch_bounds__(256) void gemm_naive_kernel(const int* __restrict__ a,
                                                         const int* __restrict__ b,
                                                         int* __restrict__ C) {
    const int col = blockIdx.x * 256 + threadIdx.x;
    const int row = blockIdx.y;
    int acc = 0;
    for (int k = 0; k < K_DIM; ++k)
        acc += a[(size_t)row * K_DIM + k] * b[(size_t)k * N_DIM + col];
    C[(size_t)row * N_DIM + col] = sat8(acc);
}

extern "C" void kernel_launch(void* const* d_in, const int* in_sizes, int n_in,
                              void* d_out, int out_size, void* d_ws, size_t ws_size,
                              hipStream_t stream) {
    const int* a = (const int*)d_in[0];
    const int* b = (const int*)d_in[1];
    // alpha_row (d_in[2]) / alpha_col (d_in[3]) are unused in this variant.
    int* out = (int*)d_out;

    const size_t needed = 2 * (size_t)M_DIM * K_DIM;   // 16 MB packed operands
    if (ws_size < needed) {
        gemm_naive_kernel<<<dim3(N_DIM / 256, M_DIM), 256, 0, stream>>>(a, b, out);
        return;
    }

    char* A8 = (char*)d_ws;                          // 8 MB
    char* B8 = A8 + (size_t)M_DIM * K_DIM;           // 8 MB

    pack_a_kernel<<<(M_DIM * K_DIM / 4) / 256, 256, 0, stream>>>(a, (int*)A8);
    pack_b_kernel<<<dim3(N_DIM / 64, K_DIM / 64), 256, 0, stream>>>(b, B8);
    gemm_i8_kernel<<<dim3(N_DIM / 128, M_DIM / 128), 256, 0, stream>>>(A8, B8, out);
}